// Round 5
// baseline (33.456 us; speedup 1.0000x reference)
//
#include <hip/hip_runtime.h>

// ---- problem constants ----
// B=16, N=512, D_MODEL=256, NUM_RBF=50, CUTOFF=12
// delta = 12/49, width = 2*delta
// S = 2.45229158;  D = delta*S = sqrt(log2 e)/2 = 0.60056098
// g_k = 2^{-(dS - kD)^2}; within chunk c (10 k's, r=0..9):
//   t''_r = t0 * Ac^r   (pure geometric, M = Ac^2 per pair-step)
//   g     = t'' * e^{-r^2/4}   (j-independent, applied once at the end)
#define S_C     2.45229158f
#define TWO_DS  1.20112241f   /* 2*D */
#define TEN_D   6.00560980f   /* 10*D */

typedef float v2f __attribute__((ext_vector_type(2)));

__device__ __forceinline__ float fast_exp2(float x) {
#if __has_builtin(__builtin_amdgcn_exp2f)
    return __builtin_amdgcn_exp2f(x);
#else
    float r;
    asm("v_exp_f32 %0, %1" : "=v"(r) : "v"(x));
    return r;
#endif
}
__device__ __forceinline__ float fast_sqrt(float x) {
#if __has_builtin(__builtin_amdgcn_sqrtf)
    return __builtin_amdgcn_sqrtf(x);
#else
    return sqrtf(x);
#endif
}

// sum over each quad (lanes {4q..4q+3}) via two DPP quad_perm swaps — pure VALU.
__device__ __forceinline__ float quad_sum(float x) {
    int a = __builtin_amdgcn_update_dpp(0, __float_as_int(x), 0xB1, 0xF, 0xF, true); // [1,0,3,2]
    x += __int_as_float(a);
    int b = __builtin_amdgcn_update_dpp(0, __float_as_int(x), 0x4E, 0xF, 0xF, true); // [2,3,0,1]
    x += __int_as_float(b);
    return x;
}

__constant__ const float E5tab[5] = {1.0f, 6.73794700e-3f, 4.53999298e-5f,
                                     3.05902321e-7f, 2.06115362e-9f};  // e^{-5c}

// One k-pass over chunks [C0, C0+NC): 8 neighbors, chain over k, QP scale,
// DPP quad-reduce, conditional LDS write into this wave's row matrix.
template <int C0, int NC>
__device__ __forceinline__ void rbf_pass(const float* __restrict__ posb, int l3,
                                         float pix, float piy, float piz,
                                         v2f* __restrict__ red_row, bool writer)
{
    v2f acc[NC * 5];
#pragma unroll
    for (int m = 0; m < NC * 5; ++m) acc[m] = (v2f){0.0f, 0.0f};

#pragma unroll
    for (int jj = 0; jj < 8; ++jj) {
        const float* pj = posb + jj * 192 + l3;
        const float dx = pix - pj[0];
        const float dy = piy - pj[1];
        const float dz = piz - pj[2];
        const float d2 = fmaf(dx, dx, fmaf(dy, dy, fmaf(dz, dz, 1e-8f)));
        float dS = fast_sqrt(d2) * S_C;
        dS = fminf(dS, 42.0f);                     // true values identically 0 beyond
        const float Ap = fast_exp2(dS * TWO_DS);   // 2^{2*D*dS} <= 2^50.5

#pragma unroll
        for (int ci = 0; ci < NC; ++ci) {
            constexpr int dummy = 0; (void)dummy;
            const int c = C0 + ci;
            const float u  = dS - (float)c * TEN_D;
            const float t0 = fast_exp2(-(u * u));
            const float Ac  = Ap * E5tab[c];
            const float Ac2 = Ac * Ac;             // <= 2^101, finite
            v2f g = {t0, t0 * Ac};
            acc[ci * 5 + 0] += g;
            const v2f M = {Ac2, Ac2};
#pragma unroll
            for (int t = 1; t < 5; ++t) {
                g = g * M;
                acc[ci * 5 + t] += g;
            }
        }
    }

    // j-independent e^{-r^2/4} factors (r = 2t, 2t+1), then quad pre-reduce.
    const v2f QP[5] = {{1.0f,            0.778800783f},
                       {0.367879441f,    0.105399225f},
                       {1.83156389e-2f,  1.93045414e-3f},
                       {1.23409804e-4f,  4.78511739e-6f},
                       {1.12535175e-7f,  1.60522806e-9f}};
#pragma unroll
    for (int m = 0; m < NC * 5; ++m) {
        v2f v = acc[m] * QP[m % 5];
        v.x = quad_sum(v.x);
        v.y = quad_sum(v.y);
        if (writer) red_row[C0 * 5 + m] = v;
    }
}

// One wave per output row (b,i). Lanes split the 512 neighbors (8 each).
// R4: two k-passes (<=15 v2f acc live), DPP quad pre-reduce (LDS 12.8 KB,
// no barrier — reduce matrix is wave-private).
template <bool FUSED>
__global__ __launch_bounds__(256)
void rbf_mean_kernel(const float* __restrict__ pos,
                     float* __restrict__ meanout,   // !FUSED
                     const int* __restrict__ an,    // FUSED only
                     const float* __restrict__ te,
                     const float* __restrict__ pw,
                     const float* __restrict__ pb,
                     float* __restrict__ out)
{
    __shared__ v2f red2[4][16 * 25];   // [wave][(lane>>2)*25 + m]  (12.8 KB)

    const int w    = threadIdx.x >> 6;
    const int lane = threadIdx.x & 63;
    const int row  = blockIdx.x * 4 + w;    // 0..8191
    const int b    = row >> 9;              // N = 512
    const int i    = row & 511;

    const float* posb = pos + (size_t)b * 1536;

    // row-i position via scalar path (wave-uniform)
    const int i3 = __builtin_amdgcn_readfirstlane(3 * i);
    const float pix = posb[i3 + 0];
    const float piy = posb[i3 + 1];
    const float piz = posb[i3 + 2];

    const int  l3     = lane * 3;
    const bool writer = (lane & 3) == 0;
    v2f* red_row = &red2[w][(lane >> 2) * 25];

    rbf_pass<0, 3>(posb, l3, pix, piy, piz, red_row, writer);  // k = 0..29
    rbf_pass<3, 2>(posb, l3, pix, piy, piz, red_row, writer);  // k = 30..49
    // wave-private LDS: no __syncthreads needed (compiler inserts lgkmcnt waits)

    float meanv = 0.0f;
    if (lane < 50) {
        const float* col = (const float*)&red2[w][0] + lane;
        float s0 = 0.f, s1 = 0.f, s2 = 0.f, s3 = 0.f;
#pragma unroll
        for (int r = 0; r < 16; r += 4) {
            s0 += col[(r + 0) * 50];
            s1 += col[(r + 1) * 50];
            s2 += col[(r + 2) * 50];
            s3 += col[(r + 3) * 50];
        }
        meanv = ((s0 + s1) + (s2 + s3)) * (1.0f / 512.0f);
    }

    if constexpr (!FUSED) {
        if (lane < 50) meanout[(size_t)row * 50 + lane] = meanv;
    } else {
        __shared__ float ms[4][52];          // wave-private broadcast
        if (lane < 50) ms[w][lane] = meanv;
        const int tok = an[row];
        float4 o = reinterpret_cast<const float4*>(pb)[lane];
        const float4 t = reinterpret_cast<const float4*>(te + (size_t)tok * 256)[lane];
        o.x += t.x; o.y += t.y; o.z += t.z; o.w += t.w;
#pragma unroll
        for (int k = 0; k < 50; ++k) {
            const float mk = ms[w][k];
            const float4 w4 = reinterpret_cast<const float4*>(pw + k * 256)[lane];
            o.x = fmaf(mk, w4.x, o.x);
            o.y = fmaf(mk, w4.y, o.y);
            o.z = fmaf(mk, w4.z, o.z);
            o.w = fmaf(mk, w4.w, o.w);
        }
        reinterpret_cast<float4*>(out)[(size_t)row * 64 + lane] = o;
    }
}

// out[row][:] = te[an[row]][:] + pb[:] + mean[row][:] @ pw
// 8 rows per wave, 1024 waves -> pw L2 traffic ~50 MB (~1.5 us).
__global__ __launch_bounds__(256)
void proj_kernel(const float* __restrict__ mean,
                 const int* __restrict__ an,
                 const float* __restrict__ te,
                 const float* __restrict__ pw,
                 const float* __restrict__ pb,
                 float* __restrict__ out)
{
    const int w    = threadIdx.x >> 6;
    const int lane = threadIdx.x & 63;
    int wid = blockIdx.x * 4 + w;                       // 0..1023
    wid = __builtin_amdgcn_readfirstlane(wid);          // force SGPR
    const int row0 = wid * 8;

    const float4 bias = reinterpret_cast<const float4*>(pb)[lane];
    float4 o[8];
#pragma unroll
    for (int r = 0; r < 8; ++r) {
        const int tok = an[row0 + r];                   // wave-uniform
        const float4 t = reinterpret_cast<const float4*>(te + (size_t)tok * 256)[lane];
        o[r].x = bias.x + t.x; o[r].y = bias.y + t.y;
        o[r].z = bias.z + t.z; o[r].w = bias.w + t.w;
    }
#pragma unroll
    for (int k = 0; k < 50; ++k) {
        const float4 w4 = reinterpret_cast<const float4*>(pw + (size_t)k * 256)[lane];
#pragma unroll
        for (int r = 0; r < 8; ++r) {
            const float mk = mean[(size_t)(row0 + r) * 50 + k];  // wave-uniform
            o[r].x = fmaf(mk, w4.x, o[r].x);
            o[r].y = fmaf(mk, w4.y, o[r].y);
            o[r].z = fmaf(mk, w4.z, o[r].z);
            o[r].w = fmaf(mk, w4.w, o[r].w);
        }
    }
#pragma unroll
    for (int r = 0; r < 8; ++r)
        reinterpret_cast<float4*>(out)[(size_t)(row0 + r) * 64 + lane] = o[r];
}

extern "C" void kernel_launch(void* const* d_in, const int* in_sizes, int n_in,
                              void* d_out, int out_size, void* d_ws, size_t ws_size,
                              hipStream_t stream)
{
    const int*   an  = (const int*)  d_in[0];   // [16,512] int32
    const float* pos = (const float*)d_in[1];   // [16,512,3]
    const float* te  = (const float*)d_in[2];   // [100,256]
    const float* pw  = (const float*)d_in[3];   // [50,256]
    const float* pb  = (const float*)d_in[4];   // [256]
    float* out = (float*)d_out;                  // [16,512,256]

    const size_t mean_bytes = (size_t)8192 * 50 * sizeof(float);
    if (ws_size >= mean_bytes) {
        float* mean = (float*)d_ws;
        rbf_mean_kernel<false><<<2048, 256, 0, stream>>>(pos, mean, nullptr, nullptr,
                                                         nullptr, nullptr, nullptr);
        proj_kernel<<<256, 256, 0, stream>>>(mean, an, te, pw, pb, out);
    } else {
        rbf_mean_kernel<true><<<2048, 256, 0, stream>>>(pos, nullptr, an, te, pw, pb, out);
    }
}

// Round 6
// 27.314 us; speedup vs baseline: 1.2248x; 1.2248x over previous
//
#include <hip/hip_runtime.h>

// ---- problem constants ----
// B=16, N=512, D_MODEL=256, NUM_RBF=50, CUTOFF=12
// delta = 12/49, width = 2*delta
// S = 2.45229158;  D = delta*S = sqrt(log2 e)/2 = 0.60056098
// Key identity: 4*D^2 = log2(e)  =>  2^{-m*D^2} = e^{-m/4}
// g_k (k = 10c + r, r in [0,10)):
//   u  = dS - 10c*D
//   g  = 2^{-u^2} * (2^{2D*u})^r * e^{-r^2/4}
//      = t0 * Ac^r * e^{-r^2/4}     (pure geometric chain in r)
// Ac = Ap * e^{-5c},  Ap = 2^{2D*dS};  e^{-r^2/4} is j-independent -> applied once.
#define S_C     2.45229158f
#define TWO_DS  1.20112241f   /* 2*D */
#define TEN_D   6.00560980f   /* 10*D */
#define E5_1 6.73794700e-3f   /* e^-5  */
#define E5_2 4.53999298e-5f   /* e^-10 */
#define E5_3 3.05902321e-7f   /* e^-15 */
#define E5_4 2.06115362e-9f   /* e^-20 */

typedef float v2f __attribute__((ext_vector_type(2)));

__device__ __forceinline__ float fast_exp2(float x) {
#if __has_builtin(__builtin_amdgcn_exp2f)
    return __builtin_amdgcn_exp2f(x);
#else
    float r;
    asm("v_exp_f32 %0, %1" : "=v"(r) : "v"(x));
    return r;
#endif
}
__device__ __forceinline__ float fast_sqrt(float x) {
#if __has_builtin(__builtin_amdgcn_sqrtf)
    return __builtin_amdgcn_sqrtf(x);
#else
    return sqrtf(x);
#endif
}

// Single fused kernel. One wave per output row (b,i):
//   phase 1 (R2 core): 8 neighbors/lane, 5 geometric chunks, 25 v2f acc
//   phase 2: QP scale, shfl_xor(1) pair-reduce, wave-private LDS matrix,
//            lane<50 column-sum -> mean[k]
//   phase 3: epilogue out[row] = te[an[row]] + pb + mean @ pw (wave-private)
// No __syncthreads anywhere: all LDS is wave-private.
__global__ __launch_bounds__(256)
void rbf_fused_kernel(const float* __restrict__ pos,
                      const int* __restrict__ an,
                      const float* __restrict__ te,
                      const float* __restrict__ pw,
                      const float* __restrict__ pb,
                      float* __restrict__ out)
{
    __shared__ v2f   red2[4][32 * 25];   // [wave][(lane/2)*25 + m]  25.6 KB
    __shared__ float ms[4][52];          // wave-private mean broadcast

    const int w    = threadIdx.x >> 6;
    const int lane = threadIdx.x & 63;
    const int row  = blockIdx.x * 4 + w;    // 0..8191
    const int b    = row >> 9;              // N = 512
    const int i    = row & 511;

    const float* posb = pos + (size_t)b * 1536;

    // preload this lane's 8 neighbor positions (R2 structure — best known)
    float jx[8], jy[8], jz[8];
#pragma unroll
    for (int jj = 0; jj < 8; ++jj) {
        const int j = jj * 64 + lane;
        jx[jj] = posb[j * 3 + 0];
        jy[jj] = posb[j * 3 + 1];
        jz[jj] = posb[j * 3 + 2];
    }
    const float pix = posb[i * 3 + 0];
    const float piy = posb[i * 3 + 1];
    const float piz = posb[i * 3 + 2];

    v2f acc[25];   // acc[5c+t] = sum_j {t''_{2t}, t''_{2t+1}} of chunk c
#pragma unroll
    for (int m = 0; m < 25; ++m) acc[m] = (v2f){0.0f, 0.0f};

#pragma unroll
    for (int jj = 0; jj < 8; ++jj) {
        const float dx = pix - jx[jj];
        const float dy = piy - jy[jj];
        const float dz = piz - jz[jj];
        const float d2 = fmaf(dx, dx, fmaf(dy, dy, fmaf(dz, dz, 1e-8f)));
        float dS = fast_sqrt(d2) * S_C;
        dS = fminf(dS, 42.0f);            // true values identically 0 beyond
        const float Ap = fast_exp2(dS * TWO_DS);   // 2^{2D*dS} <= 2^50.5

#pragma unroll
        for (int c = 0; c < 5; ++c) {
            const float u  = dS - (float)c * TEN_D;
            const float t0 = fast_exp2(-(u * u));
            const float Ac  = (c == 0) ? Ap :
                              (c == 1) ? Ap * E5_1 :
                              (c == 2) ? Ap * E5_2 :
                              (c == 3) ? Ap * E5_3 : Ap * E5_4;
            const float Ac2 = Ac * Ac;    // <= 2^101, finite
            v2f g = {t0, t0 * Ac};
            acc[5 * c + 0] += g;
            const v2f M = {Ac2, Ac2};
#pragma unroll
            for (int t = 1; t < 5; ++t) {
                g = g * M;
                acc[5 * c + t] += g;
            }
        }
    }

    // j-independent e^{-r^2/4} factors (r = 2t, 2t+1)
    {
        const v2f QP[5] = {{1.0f,            0.778800783f},
                           {0.367879441f,    0.105399225f},
                           {1.83156389e-2f,  1.93045414e-3f},
                           {1.23409804e-4f,  4.78511739e-6f},
                           {1.12535175e-7f,  1.60522806e-9f}};
#pragma unroll
        for (int m = 0; m < 25; ++m) acc[m] = acc[m] * QP[m % 5];
    }

    // pair-reduce via shfl_xor(1); even lanes write the 32x25-v2f LDS matrix
#pragma unroll
    for (int m = 0; m < 25; ++m) {
        const float lx = __shfl_xor(acc[m].x, 1);
        const float ly = __shfl_xor(acc[m].y, 1);
        acc[m] += (v2f){lx, ly};
    }
    if ((lane & 1) == 0) {
        v2f* myrow = &red2[w][(lane >> 1) * 25];
#pragma unroll
        for (int m = 0; m < 25; ++m) myrow[m] = acc[m];
    }
    // wave-private LDS: in-wave lgkmcnt ordering suffices, no barrier

    if (lane < 50) {
        const float* col = (const float*)&red2[w][0] + lane;
        float s0 = 0.f, s1 = 0.f, s2 = 0.f, s3 = 0.f;
#pragma unroll
        for (int r = 0; r < 32; r += 4) {
            s0 += col[(r + 0) * 50];
            s1 += col[(r + 1) * 50];
            s2 += col[(r + 2) * 50];
            s3 += col[(r + 3) * 50];
        }
        ms[w][lane] = ((s0 + s1) + (s2 + s3)) * (1.0f / 512.0f);
    }

    // ---- fused projection epilogue (wave-private) ----
    const int tok = an[row];                 // wave-uniform -> scalar load
    float4 o = reinterpret_cast<const float4*>(pb)[lane];
    const float4 t = reinterpret_cast<const float4*>(te + (size_t)tok * 256)[lane];
    o.x += t.x; o.y += t.y; o.z += t.z; o.w += t.w;
#pragma unroll
    for (int k = 0; k < 50; ++k) {
        const float mk = ms[w][k];           // uniform LDS broadcast
        const float4 w4 = reinterpret_cast<const float4*>(pw + k * 256)[lane];
        o.x = fmaf(mk, w4.x, o.x);
        o.y = fmaf(mk, w4.y, o.y);
        o.z = fmaf(mk, w4.z, o.z);
        o.w = fmaf(mk, w4.w, o.w);
    }
    reinterpret_cast<float4*>(out)[(size_t)row * 64 + lane] = o;
}

extern "C" void kernel_launch(void* const* d_in, const int* in_sizes, int n_in,
                              void* d_out, int out_size, void* d_ws, size_t ws_size,
                              hipStream_t stream)
{
    const int*   an  = (const int*)  d_in[0];   // [16,512] int32
    const float* pos = (const float*)d_in[1];   // [16,512,3]
    const float* te  = (const float*)d_in[2];   // [100,256]
    const float* pw  = (const float*)d_in[3];   // [50,256]
    const float* pb  = (const float*)d_in[4];   // [256]
    float* out = (float*)d_out;                  // [16,512,256]

    rbf_fused_kernel<<<2048, 256, 0, stream>>>(pos, an, te, pw, pb, out);
}